// Round 5
// baseline (959.622 us; speedup 1.0000x reference)
//
#include <hip/hip_runtime.h>

#define S_LEN 2048
#define H_DIM 1024
#define NHEAD 8
#define D_HEAD 128
#define KSPLIT 4
#define KV_PER (S_LEN / KSPLIT)  // 512 kv positions per split

typedef __bf16 bf16x8 __attribute__((ext_vector_type(8)));
typedef float floatx4 __attribute__((ext_vector_type(4)));

__device__ __forceinline__ float b2f(unsigned short u) {
    union { unsigned int i; float f; } v;
    v.i = ((unsigned int)u) << 16;
    return v.f;
}
__device__ __forceinline__ unsigned short f2b(float f) {
    union { float f; unsigned int i; } v;
    v.f = f;
    return (unsigned short)((v.i + 0x7fffu + ((v.i >> 16) & 1u)) >> 16);
}

// ---------------- positional encoding + input add (fp32 in -> fp32 + bf16 out) ----------------
__global__ __launch_bounds__(256) void posenc_kernel(
    const float* __restrict__ in, float* __restrict__ xf,
    unsigned short* __restrict__ xb)
{
    int g = blockIdx.x * 256 + threadIdx.x;
    int s = g >> 10;
    int h = g & 1023;
    float dv = powf(10000.0f, -(float)h * (1.0f / 512.0f));
    float ang = (float)s * dv;
    float pe = (h & 1) ? cosf(ang) : sinf(ang);
    float x = in[g] + pe;
    xf[g] = x;
    xb[g] = f2b(x);
}

// ---------------- fp32 -> bf16 transpose (per head, [R,C] -> [C,R]) ----------------
__global__ __launch_bounds__(256) void transpose_f2b(
    const float* __restrict__ in, unsigned short* __restrict__ out, int R, int C)
{
    __shared__ unsigned short tile[32][33];
    const float* ih = in + (size_t)blockIdx.z * R * C;
    unsigned short* oh = out + (size_t)blockIdx.z * R * C;
    int r0 = blockIdx.y * 32, c0 = blockIdx.x * 32;
    int tx = threadIdx.x, ty = threadIdx.y;
    for (int i = ty; i < 32; i += 8)
        tile[i][tx] = f2b(ih[(size_t)(r0 + i) * C + c0 + tx]);
    __syncthreads();
    for (int i = ty; i < 32; i += 8)
        oh[(size_t)(c0 + i) * R + r0 + tx] = tile[tx][i];
}

// ---------------- GEMM: C[M,N] = A[M,K] @ Bt[N,K]^T + bias ----------------
// 64x64 tile, BK=64, 4 waves (each 32x32), reg-prefetch pipeline. 512 blocks -> 2/CU.
// MODE 0: bf16 out [M,N]; MODE 1: bf16 out transposed [N, ldt]; MODE 2: f32 out [M,N]
template <int MODE, bool RELU>
__global__ __launch_bounds__(256) void gemm_bt(
    const unsigned short* __restrict__ A, const unsigned short* __restrict__ Bt,
    const float* __restrict__ bias, float* __restrict__ Cf,
    unsigned short* __restrict__ Cb, int M, int N, int K, int ldt)
{
    constexpr int KS = 64 * 8 + 8;  // 520 shorts per kseg slab (+8 pad)
    __shared__ __align__(16) unsigned short sA[8 * KS];
    __shared__ __align__(16) unsigned short sB[8 * KS];
    const int tid = threadIdx.x;
    const int wave = tid >> 6, lane = tid & 63;
    const int quad = lane >> 4, l16 = lane & 15;
    const int i0 = blockIdx.y * 64, j0 = blockIdx.x * 64;
    const int wm = (wave >> 1) * 32, wn = (wave & 1) * 32;
    const int row = tid >> 2, ks2 = (tid & 3) * 2;  // staging: row 0..63, kseg pair

    const unsigned short* Ap = A + (size_t)(i0 + row) * K + ks2 * 8;
    const unsigned short* Bp = Bt + (size_t)(j0 + row) * K + ks2 * 8;
    unsigned short* sAp = sA + ks2 * KS + row * 8;
    unsigned short* sBp = sB + ks2 * KS + row * 8;

    floatx4 z4 = {0.f, 0.f, 0.f, 0.f};
    floatx4 acc[2][2];
#pragma unroll
    for (int i = 0; i < 2; i++)
#pragma unroll
        for (int j = 0; j < 2; j++) acc[i][j] = z4;

    uint4 a0 = *(const uint4*)(Ap);
    uint4 a1 = *(const uint4*)(Ap + 8);
    uint4 b0 = *(const uint4*)(Bp);
    uint4 b1 = *(const uint4*)(Bp + 8);

    for (int k0 = 0; k0 < K; k0 += 64) {
        __syncthreads();
        *(uint4*)sAp = a0;
        *(uint4*)(sAp + KS) = a1;
        *(uint4*)sBp = b0;
        *(uint4*)(sBp + KS) = b1;
        __syncthreads();
        if (k0 + 64 < K) {  // prefetch next K-slab; overlaps the 8 MFMAs below
            a0 = *(const uint4*)(Ap + k0 + 64);
            a1 = *(const uint4*)(Ap + k0 + 72);
            b0 = *(const uint4*)(Bp + k0 + 64);
            b1 = *(const uint4*)(Bp + k0 + 72);
        }
#pragma unroll
        for (int kh = 0; kh < 2; kh++) {
            bf16x8 af[2], bfr[2];
#pragma unroll
            for (int mi = 0; mi < 2; mi++)
                af[mi] = *(const bf16x8*)(sA + (kh * 4 + quad) * KS + (wm + mi * 16 + l16) * 8);
#pragma unroll
            for (int ni = 0; ni < 2; ni++)
                bfr[ni] = *(const bf16x8*)(sB + (kh * 4 + quad) * KS + (wn + ni * 16 + l16) * 8);
#pragma unroll
            for (int mi = 0; mi < 2; mi++)
#pragma unroll
                for (int ni = 0; ni < 2; ni++)
                    acc[mi][ni] = __builtin_amdgcn_mfma_f32_16x16x32_bf16(
                        af[mi], bfr[ni], acc[mi][ni], 0, 0, 0);
        }
    }

#pragma unroll
    for (int mi = 0; mi < 2; mi++) {
#pragma unroll
        for (int ni = 0; ni < 2; ni++) {
            const int col = j0 + wn + ni * 16 + l16;
            const float bval = bias[col];
#pragma unroll
            for (int r = 0; r < 4; r++) {
                const int row_o = i0 + wm + mi * 16 + quad * 4 + r;  // C/D: row=quad*4+reg
                float v = acc[mi][ni][r] + bval;
                if (RELU) v = fmaxf(v, 0.0f);
                if (MODE == 0) Cb[(size_t)row_o * N + col] = f2b(v);
                else if (MODE == 1) Cb[(size_t)col * ldt + row_o] = f2b(v);
                else Cf[(size_t)row_o * N + col] = v;
            }
        }
    }
}

// ---------------- flash attention, KV-split, no-max softmax (scores provably small) ----
// block = (64 q rows, head, split); P reuses own-wave sK rows; K/V reg-prefetch.
// NOTE: no min-waves clamp — round-4's (256,4) capped VGPR at 56 and spilled ~250 MB
// of scratch traffic per dispatch (WRITE_SIZE 240 MB). Let the allocator breathe.
__global__ __launch_bounds__(256) void flash_attn(
    const unsigned short* __restrict__ Qg, const unsigned short* __restrict__ Kg,
    const unsigned short* __restrict__ Vt, unsigned short* __restrict__ Op,
    float* __restrict__ Lp)
{
    constexpr int LD = 136;   // K tile row pad
    constexpr int VLD = 72;   // V^T tile row pad
    __shared__ __align__(16) unsigned short sK[64 * LD];    // [t][d]; also P (per-wave rows)
    __shared__ __align__(16) unsigned short sV[128 * VLD];  // [d][t]

    const int tid = threadIdx.x;
    const int wave = tid >> 6, lane = tid & 63;
    const int quad = lane >> 4, l16 = lane & 15;
    const int head = blockIdx.y;
    const int q0 = blockIdx.x * 64;
    const int split = blockIdx.z;
    const int h0 = head * D_HEAD;

    // Q fragments direct from global (loop-invariant)
    bf16x8 aq[4];
    const int qrow = q0 + wave * 16 + l16;
#pragma unroll
    for (int ks = 0; ks < 4; ks++)
        aq[ks] = *(const bf16x8*)(Qg + (size_t)qrow * H_DIM + h0 + ks * 32 + quad * 8);

    unsigned short* myP = sK + (wave * 16) * LD;  // own-wave 16 rows of sK

    const int krr = tid >> 4;            // t row 0..15 (+16*it)
    const int kcc = (tid & 15) * 8;      // d
    const int vrr = tid >> 3;            // d row 0..31 (+32*it)
    const int vcc = (tid & 7) * 8;       // t

    floatx4 z4 = {0.f, 0.f, 0.f, 0.f};
    floatx4 o[8];
#pragma unroll
    for (int i = 0; i < 8; i++) o[i] = z4;
    float l_r[4] = {0.f, 0.f, 0.f, 0.f};

    const unsigned short* Kbase = Kg + h0;
    const unsigned short* Vbase = Vt + (size_t)h0 * S_LEN;
    const int kt0 = split * KV_PER;

    uint4 kreg[4], vreg[4];
#pragma unroll
    for (int it = 0; it < 4; it++) {
        kreg[it] = *(const uint4*)(Kbase + (size_t)(kt0 + krr + it * 16) * H_DIM + kcc);
        vreg[it] = *(const uint4*)(Vbase + (size_t)(vrr + it * 32) * S_LEN + kt0 + vcc);
    }

    for (int it0 = 0; it0 < KV_PER; it0 += 64) {
        __syncthreads();  // (a) prior PV reads of sV / own-P done
#pragma unroll
        for (int it = 0; it < 4; it++) {
            *(uint4*)(sK + (krr + it * 16) * LD + kcc) = kreg[it];
            *(uint4*)(sV + (vrr + it * 32) * VLD + vcc) = vreg[it];
        }
        __syncthreads();  // (b) staging visible

        if (it0 + 64 < KV_PER) {  // prefetch next tile; overlaps QK+exp below
            const int nk = kt0 + it0 + 64;
#pragma unroll
            for (int it = 0; it < 4; it++) {
                kreg[it] = *(const uint4*)(Kbase + (size_t)(nk + krr + it * 16) * H_DIM + kcc);
                vreg[it] = *(const uint4*)(Vbase + (size_t)(vrr + it * 32) * S_LEN + nk + vcc);
            }
        }

        // scores S[16 q][64 t] = Q K^T
        floatx4 sc[4];
#pragma unroll
        for (int ni = 0; ni < 4; ni++) {
            sc[ni] = z4;
#pragma unroll
            for (int ks = 0; ks < 4; ks++) {
                bf16x8 bk = *(const bf16x8*)(sK + (ni * 16 + l16) * LD + ks * 32 + quad * 8);
                sc[ni] = __builtin_amdgcn_mfma_f32_16x16x32_bf16(aq[ks], bk, sc[ni], 0, 0, 0);
            }
        }

        // exp without max subtraction (|s/32| small, provably no overflow); per-lane l partial
#pragma unroll
        for (int ni = 0; ni < 4; ni++)
#pragma unroll
            for (int r = 0; r < 4; r++) {
                float p = __expf(sc[ni][r] * 0.03125f);
                sc[ni][r] = p;
                l_r[r] += p;
            }

        __syncthreads();  // (c) all waves done reading sK for QK -> safe to write P
#pragma unroll
        for (int ni = 0; ni < 4; ni++)
#pragma unroll
            for (int r = 0; r < 4; r++) {
                int prow = quad * 4 + r;
                myP[prow * LD + ((ni * 16 + l16) ^ ((prow & 8) << 1))] = f2b(sc[ni][r]);
            }
        bf16x8 ap[2];
#pragma unroll
        for (int ks = 0; ks < 2; ks++)
            ap[ks] = *(const bf16x8*)(myP + l16 * LD + ((ks * 32 + quad * 8) ^ ((l16 & 8) << 1)));
#pragma unroll
        for (int ni = 0; ni < 8; ni++) {
#pragma unroll
            for (int ks = 0; ks < 2; ks++) {
                bf16x8 bv = *(const bf16x8*)(sV + (ni * 16 + l16) * VLD + ks * 32 + quad * 8);
                o[ni] = __builtin_amdgcn_mfma_f32_16x16x32_bf16(ap[ks], bv, o[ni], 0, 0, 0);
            }
        }
    }

    // one-time l reduction across the 16-lane groups
#pragma unroll
    for (int r = 0; r < 4; r++)
#pragma unroll
        for (int off = 1; off < 16; off <<= 1)
            l_r[r] += __shfl_xor(l_r[r], off, 64);

#pragma unroll
    for (int r = 0; r < 4; r++) {
        float inv = 1.0f / l_r[r];
        int row = q0 + wave * 16 + quad * 4 + r;
#pragma unroll
        for (int ni = 0; ni < 8; ni++)
            Op[((size_t)split * S_LEN + row) * H_DIM + h0 + ni * 16 + l16] =
                f2b(o[ni][r] * inv);
        if (l16 == 0)
            Lp[(split * NHEAD + head) * S_LEN + row] = l_r[r];
    }
}

// ---------------- merge KV-split partials + residual add + LayerNorm ----------------
__global__ __launch_bounds__(256) void merge_add_layernorm(
    const float* __restrict__ t, const unsigned short* __restrict__ Op,
    const float* __restrict__ Lp,
    float* __restrict__ of, unsigned short* __restrict__ ob)
{
    __shared__ float red[8];
    const int row = blockIdx.x, tid = threadIdx.x;
    const int head = tid >> 5;  // 32 threads per head (128 dims / 4)
    const size_t base = (size_t)row * H_DIM + tid * 4;

    float l_s[KSPLIT];
    ushort4 os[KSPLIT];
#pragma unroll
    for (int sp = 0; sp < KSPLIT; sp++) {
        os[sp] = *(const ushort4*)(Op + ((size_t)sp * S_LEN + row) * H_DIM + tid * 4);
        l_s[sp] = Lp[(sp * NHEAD + head) * S_LEN + row];
    }
    float W = 0.f, a0 = 0.f, a1 = 0.f, a2 = 0.f, a3 = 0.f;
#pragma unroll
    for (int sp = 0; sp < KSPLIT; sp++) {
        float w = l_s[sp];  // no-max softmax: weight is the raw partial sum
        W += w;
        a0 += w * b2f(os[sp].x);
        a1 += w * b2f(os[sp].y);
        a2 += w * b2f(os[sp].z);
        a3 += w * b2f(os[sp].w);
    }
    float inv = 1.0f / W;
    float4 x = *(const float4*)(t + base);
    float v0 = x.x + a0 * inv, v1 = x.y + a1 * inv;
    float v2 = x.z + a2 * inv, v3 = x.w + a3 * inv;

    float s = v0 + v1 + v2 + v3;
    float q = v0 * v0 + v1 * v1 + v2 * v2 + v3 * v3;
#pragma unroll
    for (int off = 32; off >= 1; off >>= 1) {
        s += __shfl_xor(s, off, 64);
        q += __shfl_xor(q, off, 64);
    }
    if ((tid & 63) == 0) { red[tid >> 6] = s; red[4 + (tid >> 6)] = q; }
    __syncthreads();
    s = red[0] + red[1] + red[2] + red[3];
    q = red[4] + red[5] + red[6] + red[7];
    const float mean = s * (1.0f / (float)H_DIM);
    const float var = q * (1.0f / (float)H_DIM) - mean * mean;
    const float rstd = rsqrtf(var + 1e-5f);
    float o0 = (v0 - mean) * rstd, o1 = (v1 - mean) * rstd;
    float o2 = (v2 - mean) * rstd, o3 = (v3 - mean) * rstd;
    *(float4*)(of + base) = make_float4(o0, o1, o2, o3);
    *(ushort4*)(ob + base) = make_ushort4(f2b(o0), f2b(o1), f2b(o2), f2b(o3));
}

// ---------------- fused residual add + LayerNorm (fp32 in -> fp32 + bf16 out) ----------------
__global__ __launch_bounds__(256) void add_layernorm(
    const float* __restrict__ a, const float* __restrict__ b,
    float* __restrict__ of, unsigned short* __restrict__ ob)
{
    __shared__ float red[8];
    const int row = blockIdx.x, tid = threadIdx.x;
    const size_t base = (size_t)row * H_DIM + tid * 4;
    float4 x = *(const float4*)(a + base);
    float4 y = *(const float4*)(b + base);
    float v0 = x.x + y.x, v1 = x.y + y.y, v2 = x.z + y.z, v3 = x.w + y.w;
    float s = v0 + v1 + v2 + v3;
    float q = v0 * v0 + v1 * v1 + v2 * v2 + v3 * v3;
#pragma unroll
    for (int off = 32; off >= 1; off >>= 1) {
        s += __shfl_xor(s, off, 64);
        q += __shfl_xor(q, off, 64);
    }
    if ((tid & 63) == 0) { red[tid >> 6] = s; red[4 + (tid >> 6)] = q; }
    __syncthreads();
    s = red[0] + red[1] + red[2] + red[3];
    q = red[4] + red[5] + red[6] + red[7];
    const float mean = s * (1.0f / (float)H_DIM);
    const float var = q * (1.0f / (float)H_DIM) - mean * mean;
    const float rstd = rsqrtf(var + 1e-5f);
    float o0 = (v0 - mean) * rstd, o1 = (v1 - mean) * rstd;
    float o2 = (v2 - mean) * rstd, o3 = (v3 - mean) * rstd;
    *(float4*)(of + base) = make_float4(o0, o1, o2, o3);
    *(ushort4*)(ob + base) = make_ushort4(f2b(o0), f2b(o1), f2b(o2), f2b(o3));
}

extern "C" void kernel_launch(void* const* d_in, const int* in_sizes, int n_in,
                              void* d_out, int out_size, void* d_ws, size_t ws_size,
                              hipStream_t stream)
{
    (void)in_sizes; (void)n_in; (void)out_size; (void)ws_size;
    const float* in = (const float*)d_in[0];
    const float* Wq = (const float*)d_in[1];
    const float* bq = (const float*)d_in[2];
    const float* Wk = (const float*)d_in[3];
    const float* bk = (const float*)d_in[4];
    const float* Wv = (const float*)d_in[5];
    const float* bv = (const float*)d_in[6];
    const float* W1 = (const float*)d_in[7];
    const float* b1 = (const float*)d_in[8];
    const float* W2 = (const float*)d_in[9];
    const float* b2 = (const float*)d_in[10];

    char* ws = (char*)d_ws;
    const size_t MB = 1024 * 1024;
    float* t_f32 = (float*)(ws + 0 * MB);                    // 8 MB
    float* cf_f32 = (float*)(ws + 8 * MB);                   // 8 MB (ff2)
    unsigned short* t_b = (unsigned short*)(ws + 16 * MB);   // 4 MB
    unsigned short* K_b = (unsigned short*)(ws + 20 * MB);   // 4 MB
    unsigned short* Vt_b = (unsigned short*)(ws + 24 * MB);  // 4 MB, [NH,D,S]
    unsigned short* Q_b = (unsigned short*)(ws + 28 * MB);   // 4 MB (also ff1)
    unsigned short* WqT = (unsigned short*)(ws + 32 * MB);   // 2 MB each, [N,K]
    unsigned short* WkT = (unsigned short*)(ws + 34 * MB);
    unsigned short* WvT = (unsigned short*)(ws + 36 * MB);
    unsigned short* W1T = (unsigned short*)(ws + 38 * MB);
    unsigned short* W2T = (unsigned short*)(ws + 40 * MB);
    unsigned short* Op = (unsigned short*)(ws + 42 * MB);    // 16 MB [split][S][H] bf16
    float* Lp = (float*)(ws + 58 * MB);                      // 256 KB [split][NH][S]

    dim3 tb(32, 8);
    transpose_f2b<<<dim3(4, 32, 8), tb, 0, stream>>>(Wq, WqT, H_DIM, D_HEAD);
    transpose_f2b<<<dim3(4, 32, 8), tb, 0, stream>>>(Wk, WkT, H_DIM, D_HEAD);
    transpose_f2b<<<dim3(4, 32, 8), tb, 0, stream>>>(Wv, WvT, H_DIM, D_HEAD);
    transpose_f2b<<<dim3(32, 32, 1), tb, 0, stream>>>(W1, W1T, H_DIM, H_DIM);
    transpose_f2b<<<dim3(32, 32, 1), tb, 0, stream>>>(W2, W2T, H_DIM, H_DIM);

    posenc_kernel<<<(S_LEN * H_DIM) / 256, 256, 0, stream>>>(in, t_f32, t_b);

    dim3 gg(H_DIM / 64, S_LEN / 64);  // 16 x 32 = 512 blocks -> 2/CU
    gemm_bt<0, false><<<gg, 256, 0, stream>>>(t_b, WkT, bk, nullptr, K_b, S_LEN, H_DIM, H_DIM, 0);
    gemm_bt<1, false><<<gg, 256, 0, stream>>>(t_b, WvT, bv, nullptr, Vt_b, S_LEN, H_DIM, H_DIM, S_LEN);

    for (int layer = 0; layer < 6; layer++) {
        gemm_bt<0, false><<<gg, 256, 0, stream>>>(t_b, WqT, bq, nullptr, Q_b, S_LEN, H_DIM, H_DIM, 0);
        flash_attn<<<dim3(S_LEN / 64, NHEAD, KSPLIT), 256, 0, stream>>>(Q_b, K_b, Vt_b, Op, Lp);
        merge_add_layernorm<<<S_LEN, 256, 0, stream>>>(t_f32, Op, Lp, t_f32, t_b);
        gemm_bt<0, true><<<gg, 256, 0, stream>>>(t_b, W1T, b1, nullptr, Q_b, S_LEN, H_DIM, H_DIM, 0);
        gemm_bt<2, false><<<gg, 256, 0, stream>>>(Q_b, W2T, b2, cf_f32, nullptr, S_LEN, H_DIM, H_DIM, 0);
        float* of = (layer == 5) ? (float*)d_out : t_f32;
        add_layernorm<<<S_LEN, 256, 0, stream>>>(t_f32, cf_f32, of, t_b);
    }
}

// Round 6
// 633.001 us; speedup vs baseline: 1.5160x; 1.5160x over previous
//
#include <hip/hip_runtime.h>

#define S_LEN 2048
#define H_DIM 1024
#define NHEAD 8
#define D_HEAD 128
#define KSPLIT 4
#define KV_PER (S_LEN / KSPLIT)  // 512 kv positions per split

typedef __bf16 bf16x8 __attribute__((ext_vector_type(8)));
typedef float floatx4 __attribute__((ext_vector_type(4)));

__device__ __forceinline__ float b2f(unsigned short u) {
    union { unsigned int i; float f; } v;
    v.i = ((unsigned int)u) << 16;
    return v.f;
}
__device__ __forceinline__ unsigned short f2b(float f) {
    union { float f; unsigned int i; } v;
    v.f = f;
    return (unsigned short)((v.i + 0x7fffu + ((v.i >> 16) & 1u)) >> 16);
}

// async global->LDS DMA, 16 B per lane; lds dst = wave-uniform base + lane*16
__device__ __forceinline__ void dma16(void* lds, const void* g) {
    __builtin_amdgcn_global_load_lds(
        (const __attribute__((address_space(1))) void*)g,
        (__attribute__((address_space(3))) void*)lds, 16, 0, 0);
}

// ---------------- positional encoding + input add (fp32 in -> fp32 + bf16 out) ----------------
__global__ __launch_bounds__(256) void posenc_kernel(
    const float* __restrict__ in, float* __restrict__ xf,
    unsigned short* __restrict__ xb)
{
    int g = blockIdx.x * 256 + threadIdx.x;
    int s = g >> 10;
    int h = g & 1023;
    float dv = powf(10000.0f, -(float)h * (1.0f / 512.0f));
    float ang = (float)s * dv;
    float pe = (h & 1) ? cosf(ang) : sinf(ang);
    float x = in[g] + pe;
    xf[g] = x;
    xb[g] = f2b(x);
}

// ---------------- fp32 -> bf16 transpose (per head, [R,C] -> [C,R]) ----------------
__global__ __launch_bounds__(256) void transpose_f2b(
    const float* __restrict__ in, unsigned short* __restrict__ out, int R, int C)
{
    __shared__ unsigned short tile[32][33];
    const float* ih = in + (size_t)blockIdx.z * R * C;
    unsigned short* oh = out + (size_t)blockIdx.z * R * C;
    int r0 = blockIdx.y * 32, c0 = blockIdx.x * 32;
    int tx = threadIdx.x, ty = threadIdx.y;
    for (int i = ty; i < 32; i += 8)
        tile[i][tx] = f2b(ih[(size_t)(r0 + i) * C + c0 + tx]);
    __syncthreads();
    for (int i = ty; i < 32; i += 8)
        oh[(size_t)(c0 + i) * R + r0 + tx] = tile[tx][i];
}

// ---------------- GEMM: C[M,N] = A[M,K] @ Bt[N,K]^T + bias ----------------
// 64x64 tile, BK=64, global_load_lds staging into XOR-swizzled unpadded tiles,
// double-buffered LDS: DMA of slab k+1 overlaps MFMAs on slab k. 512 blocks.
// LDS tile layout: row r (64 rows), 8 chunks of 16B; phys chunk = c ^ (r&7).
// MODE 0: bf16 out [M,N]; MODE 1: bf16 out transposed [N, ldt]; MODE 2: f32 out [M,N]
template <int MODE, bool RELU>
__global__ __launch_bounds__(256, 4) void gemm_bt(
    const unsigned short* __restrict__ A, const unsigned short* __restrict__ Bt,
    const float* __restrict__ bias, float* __restrict__ Cf,
    unsigned short* __restrict__ Cb, int M, int N, int K, int ldt)
{
    __shared__ __align__(16) unsigned short sA[2][64 * 64];
    __shared__ __align__(16) unsigned short sB[2][64 * 64];
    const int tid = threadIdx.x;
    const int wave = tid >> 6, lane = tid & 63;
    const int quad = lane >> 4, l16 = lane & 15;
    const int i0 = blockIdx.y * 64, j0 = blockIdx.x * 64;
    const int wm = (wave >> 1) * 32, wn = (wave & 1) * 32;

    // staging geometry: 8 lanes/row (16 B chunks), wave covers 8 rows/instr, 2 instr
    const int srow = lane >> 3;                       // 0..7 within wave group
    const int schunk = (lane & 7) ^ (srow & 7);       // global chunk to fetch (XOR swizzle)
    const unsigned short* Ap0 = A + (size_t)(i0 + wave * 8 + srow) * K + schunk * 8;
    const unsigned short* Ap1 = A + (size_t)(i0 + 32 + wave * 8 + srow) * K + schunk * 8;
    const unsigned short* Bp0 = Bt + (size_t)(j0 + wave * 8 + srow) * K + schunk * 8;
    const unsigned short* Bp1 = Bt + (size_t)(j0 + 32 + wave * 8 + srow) * K + schunk * 8;
    const int ld0 = (wave * 8) * 64, ld1 = (32 + wave * 8) * 64;

    floatx4 z4 = {0.f, 0.f, 0.f, 0.f};
    floatx4 acc[2][2];
#pragma unroll
    for (int i = 0; i < 2; i++)
#pragma unroll
        for (int j = 0; j < 2; j++) acc[i][j] = z4;

    // prologue: stage slab 0 into buf 0
    dma16(sA[0] + ld0, Ap0);
    dma16(sA[0] + ld1, Ap1);
    dma16(sB[0] + ld0, Bp0);
    dma16(sB[0] + ld1, Bp1);
    __syncthreads();  // drains vmcnt -> buf0 visible

    int buf = 0;
    for (int k0 = 0; k0 < K; k0 += 64) {
        if (k0 + 64 < K) {  // async-stage next slab into the other buffer
            dma16(sA[buf ^ 1] + ld0, Ap0 + k0 + 64);
            dma16(sA[buf ^ 1] + ld1, Ap1 + k0 + 64);
            dma16(sB[buf ^ 1] + ld0, Bp0 + k0 + 64);
            dma16(sB[buf ^ 1] + ld1, Bp1 + k0 + 64);
        }
        const unsigned short* cA = sA[buf];
        const unsigned short* cB = sB[buf];
#pragma unroll
        for (int kh = 0; kh < 2; kh++) {
            bf16x8 af[2], bfr[2];
#pragma unroll
            for (int mi = 0; mi < 2; mi++) {
                int row = wm + mi * 16 + l16;
                int p = (kh * 4 + quad) ^ (l16 & 7);
                af[mi] = *(const bf16x8*)(cA + row * 64 + p * 8);
            }
#pragma unroll
            for (int ni = 0; ni < 2; ni++) {
                int row = wn + ni * 16 + l16;
                int p = (kh * 4 + quad) ^ (l16 & 7);
                bfr[ni] = *(const bf16x8*)(cB + row * 64 + p * 8);
            }
#pragma unroll
            for (int mi = 0; mi < 2; mi++)
#pragma unroll
                for (int ni = 0; ni < 2; ni++)
                    acc[mi][ni] = __builtin_amdgcn_mfma_f32_16x16x32_bf16(
                        af[mi], bfr[ni], acc[mi][ni], 0, 0, 0);
        }
        __syncthreads();  // all reads of buf done + next-slab DMA drained
        buf ^= 1;
    }

#pragma unroll
    for (int mi = 0; mi < 2; mi++) {
#pragma unroll
        for (int ni = 0; ni < 2; ni++) {
            const int col = j0 + wn + ni * 16 + l16;
            const float bval = bias[col];
#pragma unroll
            for (int r = 0; r < 4; r++) {
                const int row_o = i0 + wm + mi * 16 + quad * 4 + r;  // C/D: row=quad*4+reg
                float v = acc[mi][ni][r] + bval;
                if (RELU) v = fmaxf(v, 0.0f);
                if (MODE == 0) Cb[(size_t)row_o * N + col] = f2b(v);
                else if (MODE == 1) Cb[(size_t)col * ldt + row_o] = f2b(v);
                else Cf[(size_t)row_o * N + col] = v;
            }
        }
    }
}

// ---------------- flash attention, KV-split, no-max softmax, DMA staging ----------------
// block = (64 q rows, head, split). K tile 64x128 / V^T tile 128x64, both unpadded
// with XOR-chunk swizzle; staged via global_load_lds (no staging VGPRs -> no spill).
// P overlays the dead sK region after barrier (c). __launch_bounds__(256,3): 170-reg
// budget, guaranteed spill-free (rounds 4/5: 64-reg cap spilled 250 MB/dispatch).
__global__ __launch_bounds__(256, 3) void flash_attn(
    const unsigned short* __restrict__ Qg, const unsigned short* __restrict__ Kg,
    const unsigned short* __restrict__ Vt, unsigned short* __restrict__ Op,
    float* __restrict__ Lp)
{
    __shared__ __align__(16) unsigned short sK[64 * 128];   // [t][d], swizzle key row&15
    __shared__ __align__(16) unsigned short sV[128 * 64];   // [d][t], swizzle key row&7

    const int tid = threadIdx.x;
    const int wave = tid >> 6, lane = tid & 63;
    const int quad = lane >> 4, l16 = lane & 15;
    const int head = blockIdx.y;
    const int q0 = blockIdx.x * 64;
    const int split = blockIdx.z;
    const int h0 = head * D_HEAD;

    // Q fragments direct from global (loop-invariant)
    bf16x8 aq[4];
    const int qrow = q0 + wave * 16 + l16;
#pragma unroll
    for (int ks = 0; ks < 4; ks++)
        aq[ks] = *(const bf16x8*)(Qg + (size_t)qrow * H_DIM + h0 + ks * 32 + quad * 8);

    unsigned short* myP = sK + wave * (16 * 72);  // P: 16 rows x 72 shorts, overlays sK

    // K staging: 16 lanes/row, 4 rows/instr/wave, 4 instrs (rows w*4+it*16+(lane>>4))
    const int k_r = wave * 4 + (lane >> 4);                 // LDS row mod-16 part
    const int k_c = (lane & 15) ^ (k_r & 15);               // global chunk (XOR swizzle)
    // V staging: 8 lanes/row, 8 rows/instr/wave, 4 instrs (rows w*8+it*32+(lane>>3))
    const int v_r = wave * 8 + (lane >> 3);
    const int v_c = (lane & 7) ^ (v_r & 7);

    const unsigned short* Kbase = Kg + h0;
    const unsigned short* Vbase = Vt + (size_t)h0 * S_LEN;
    const int kt0 = split * KV_PER;

    floatx4 z4 = {0.f, 0.f, 0.f, 0.f};
    floatx4 o[8];
#pragma unroll
    for (int i = 0; i < 8; i++) o[i] = z4;
    float l_r[4] = {0.f, 0.f, 0.f, 0.f};

    for (int it0 = 0; it0 < KV_PER; it0 += 64) {
        const int t0 = kt0 + it0;
        __syncthreads();  // (a) prior PV reads of sV + P-frag reads of sK done
#pragma unroll
        for (int it = 0; it < 4; it++) {
            dma16(sK + (wave * 4 + it * 16) * 128,
                  Kbase + (size_t)(t0 + k_r + it * 16) * H_DIM + k_c * 8);
            dma16(sV + (wave * 8 + it * 32) * 64,
                  Vbase + (size_t)(v_r + it * 32) * S_LEN + t0 + v_c * 8);
        }
        __syncthreads();  // (b) vmcnt drained -> tiles visible

        // scores S[16 q][64 t] = Q K^T
        floatx4 sc[4];
#pragma unroll
        for (int ni = 0; ni < 4; ni++) {
            sc[ni] = z4;
#pragma unroll
            for (int ks = 0; ks < 4; ks++) {
                int p = (ks * 4 + quad) ^ l16;  // chunk swizzle, key = row&15 = l16
                bf16x8 bk = *(const bf16x8*)(sK + (ni * 16 + l16) * 128 + p * 8);
                sc[ni] = __builtin_amdgcn_mfma_f32_16x16x32_bf16(aq[ks], bk, sc[ni], 0, 0, 0);
            }
        }

        // exp without max subtraction (scores provably small); per-lane l partial
#pragma unroll
        for (int ni = 0; ni < 4; ni++)
#pragma unroll
            for (int r = 0; r < 4; r++) {
                float p = __expf(sc[ni][r] * 0.03125f);  // 1/sqrt(H)=1/32
                sc[ni][r] = p;
                l_r[r] += p;
            }

        __syncthreads();  // (c) all waves done reading sK -> safe to overlay P
#pragma unroll
        for (int ni = 0; ni < 4; ni++)
#pragma unroll
            for (int r = 0; r < 4; r++) {
                int prow = quad * 4 + r;
                myP[prow * 72 + ((ni * 16 + l16) ^ ((prow & 8) << 1))] = f2b(sc[ni][r]);
            }
        bf16x8 ap[2];
#pragma unroll
        for (int ks = 0; ks < 2; ks++)
            ap[ks] = *(const bf16x8*)(myP + l16 * 72 + ((ks * 32 + quad * 8) ^ ((l16 & 8) << 1)));
#pragma unroll
        for (int ni = 0; ni < 8; ni++) {
#pragma unroll
            for (int ks = 0; ks < 2; ks++) {
                int p = (ks * 4 + quad) ^ (l16 & 7);  // key = row&7 = l16&7
                bf16x8 bv = *(const bf16x8*)(sV + (ni * 16 + l16) * 64 + p * 8);
                o[ni] = __builtin_amdgcn_mfma_f32_16x16x32_bf16(ap[ks], bv, o[ni], 0, 0, 0);
            }
        }
    }

    // one-time l reduction across the 16-lane groups
#pragma unroll
    for (int r = 0; r < 4; r++)
#pragma unroll
        for (int off = 1; off < 16; off <<= 1)
            l_r[r] += __shfl_xor(l_r[r], off, 64);

#pragma unroll
    for (int r = 0; r < 4; r++) {
        float inv = 1.0f / l_r[r];
        int row = q0 + wave * 16 + quad * 4 + r;
#pragma unroll
        for (int ni = 0; ni < 8; ni++)
            Op[((size_t)split * S_LEN + row) * H_DIM + h0 + ni * 16 + l16] =
                f2b(o[ni][r] * inv);
        if (l16 == 0)
            Lp[(split * NHEAD + head) * S_LEN + row] = l_r[r];
    }
}

// ---------------- merge KV-split partials + residual add + LayerNorm ----------------
__global__ __launch_bounds__(256) void merge_add_layernorm(
    const float* __restrict__ t, const unsigned short* __restrict__ Op,
    const float* __restrict__ Lp,
    float* __restrict__ of, unsigned short* __restrict__ ob)
{
    __shared__ float red[8];
    const int row = blockIdx.x, tid = threadIdx.x;
    const int head = tid >> 5;  // 32 threads per head (128 dims / 4)
    const size_t base = (size_t)row * H_DIM + tid * 4;

    float l_s[KSPLIT];
    ushort4 os[KSPLIT];
#pragma unroll
    for (int sp = 0; sp < KSPLIT; sp++) {
        os[sp] = *(const ushort4*)(Op + ((size_t)sp * S_LEN + row) * H_DIM + tid * 4);
        l_s[sp] = Lp[(sp * NHEAD + head) * S_LEN + row];
    }
    float W = 0.f, a0 = 0.f, a1 = 0.f, a2 = 0.f, a3 = 0.f;
#pragma unroll
    for (int sp = 0; sp < KSPLIT; sp++) {
        float w = l_s[sp];  // no-max softmax: weight is the raw partial sum
        W += w;
        a0 += w * b2f(os[sp].x);
        a1 += w * b2f(os[sp].y);
        a2 += w * b2f(os[sp].z);
        a3 += w * b2f(os[sp].w);
    }
    float inv = 1.0f / W;
    float4 x = *(const float4*)(t + base);
    float v0 = x.x + a0 * inv, v1 = x.y + a1 * inv;
    float v2 = x.z + a2 * inv, v3 = x.w + a3 * inv;

    float s = v0 + v1 + v2 + v3;
    float q = v0 * v0 + v1 * v1 + v2 * v2 + v3 * v3;
#pragma unroll
    for (int off = 32; off >= 1; off >>= 1) {
        s += __shfl_xor(s, off, 64);
        q += __shfl_xor(q, off, 64);
    }
    if ((tid & 63) == 0) { red[tid >> 6] = s; red[4 + (tid >> 6)] = q; }
    __syncthreads();
    s = red[0] + red[1] + red[2] + red[3];
    q = red[4] + red[5] + red[6] + red[7];
    const float mean = s * (1.0f / (float)H_DIM);
    const float var = q * (1.0f / (float)H_DIM) - mean * mean;
    const float rstd = rsqrtf(var + 1e-5f);
    float o0 = (v0 - mean) * rstd, o1 = (v1 - mean) * rstd;
    float o2 = (v2 - mean) * rstd, o3 = (v3 - mean) * rstd;
    *(float4*)(of + base) = make_float4(o0, o1, o2, o3);
    *(ushort4*)(ob + base) = make_ushort4(f2b(o0), f2b(o1), f2b(o2), f2b(o3));
}

// ---------------- fused residual add + LayerNorm (fp32 in -> fp32 + bf16 out) ----------------
__global__ __launch_bounds__(256) void add_layernorm(
    const float* __restrict__ a, const float* __restrict__ b,
    float* __restrict__ of, unsigned short* __restrict__ ob)
{
    __shared__ float red[8];
    const int row = blockIdx.x, tid = threadIdx.x;
    const size_t base = (size_t)row * H_DIM + tid * 4;
    float4 x = *(const float4*)(a + base);
    float4 y = *(const float4*)(b + base);
    float v0 = x.x + y.x, v1 = x.y + y.y, v2 = x.z + y.z, v3 = x.w + y.w;
    float s = v0 + v1 + v2 + v3;
    float q = v0 * v0 + v1 * v1 + v2 * v2 + v3 * v3;
#pragma unroll
    for (int off = 32; off >= 1; off >>= 1) {
        s += __shfl_xor(s, off, 64);
        q += __shfl_xor(q, off, 64);
    }
    if ((tid & 63) == 0) { red[tid >> 6] = s; red[4 + (tid >> 6)] = q; }
    __syncthreads();
    s = red[0] + red[1] + red[2] + red[3];
    q = red[4] + red[5] + red[6] + red[7];
    const float mean = s * (1.0f / (float)H_DIM);
    const float var = q * (1.0f / (float)H_DIM) - mean * mean;
    const float rstd = rsqrtf(var + 1e-5f);
    float o0 = (v0 - mean) * rstd, o1 = (v1 - mean) * rstd;
    float o2 = (v2 - mean) * rstd, o3 = (v3 - mean) * rstd;
    *(float4*)(of + base) = make_float4(o0, o1, o2, o3);
    *(ushort4*)(ob + base) = make_ushort4(f2b(o0), f2b(o1), f2b(o2), f2b(o3));
}

extern "C" void kernel_launch(void* const* d_in, const int* in_sizes, int n_in,
                              void* d_out, int out_size, void* d_ws, size_t ws_size,
                              hipStream_t stream)
{
    (void)in_sizes; (void)n_in; (void)out_size; (void)ws_size;
    const float* in = (const float*)d_in[0];
    const float* Wq = (const float*)d_in[1];
    const float* bq = (const float*)d_in[2];
    const float* Wk = (const float*)d_in[3];
    const float* bk = (const float*)d_in[4];
    const float* Wv = (const float*)d_in[5];
    const float* bv = (const float*)d_in[6];
    const float* W1 = (const float*)d_in[7];
    const float* b1 = (const float*)d_in[8];
    const float* W2 = (const float*)d_in[9];
    const float* b2 = (const float*)d_in[10];

    char* ws = (char*)d_ws;
    const size_t MB = 1024 * 1024;
    float* t_f32 = (float*)(ws + 0 * MB);                    // 8 MB
    float* cf_f32 = (float*)(ws + 8 * MB);                   // 8 MB (ff2)
    unsigned short* t_b = (unsigned short*)(ws + 16 * MB);   // 4 MB
    unsigned short* K_b = (unsigned short*)(ws + 20 * MB);   // 4 MB
    unsigned short* Vt_b = (unsigned short*)(ws + 24 * MB);  // 4 MB, [NH,D,S]
    unsigned short* Q_b = (unsigned short*)(ws + 28 * MB);   // 4 MB (also ff1)
    unsigned short* WqT = (unsigned short*)(ws + 32 * MB);   // 2 MB each, [N,K]
    unsigned short* WkT = (unsigned short*)(ws + 34 * MB);
    unsigned short* WvT = (unsigned short*)(ws + 36 * MB);
    unsigned short* W1T = (unsigned short*)(ws + 38 * MB);
    unsigned short* W2T = (unsigned short*)(ws + 40 * MB);
    unsigned short* Op = (unsigned short*)(ws + 42 * MB);    // 16 MB [split][S][H] bf16
    float* Lp = (float*)(ws + 58 * MB);                      // 256 KB [split][NH][S]

    dim3 tb(32, 8);
    transpose_f2b<<<dim3(4, 32, 8), tb, 0, stream>>>(Wq, WqT, H_DIM, D_HEAD);
    transpose_f2b<<<dim3(4, 32, 8), tb, 0, stream>>>(Wk, WkT, H_DIM, D_HEAD);
    transpose_f2b<<<dim3(4, 32, 8), tb, 0, stream>>>(Wv, WvT, H_DIM, D_HEAD);
    transpose_f2b<<<dim3(32, 32, 1), tb, 0, stream>>>(W1, W1T, H_DIM, H_DIM);
    transpose_f2b<<<dim3(32, 32, 1), tb, 0, stream>>>(W2, W2T, H_DIM, H_DIM);

    posenc_kernel<<<(S_LEN * H_DIM) / 256, 256, 0, stream>>>(in, t_f32, t_b);

    dim3 gg(H_DIM / 64, S_LEN / 64);  // 16 x 32 = 512 blocks
    gemm_bt<0, false><<<gg, 256, 0, stream>>>(t_b, WkT, bk, nullptr, K_b, S_LEN, H_DIM, H_DIM, 0);
    gemm_bt<1, false><<<gg, 256, 0, stream>>>(t_b, WvT, bv, nullptr, Vt_b, S_LEN, H_DIM, H_DIM, S_LEN);

    for (int layer = 0; layer < 6; layer++) {
        gemm_bt<0, false><<<gg, 256, 0, stream>>>(t_b, WqT, bq, nullptr, Q_b, S_LEN, H_DIM, H_DIM, 0);
        flash_attn<<<dim3(S_LEN / 64, NHEAD, KSPLIT), 256, 0, stream>>>(Q_b, K_b, Vt_b, Op, Lp);
        merge_add_layernorm<<<S_LEN, 256, 0, stream>>>(t_f32, Op, Lp, t_f32, t_b);
        gemm_bt<0, true><<<gg, 256, 0, stream>>>(t_b, W1T, b1, nullptr, Q_b, S_LEN, H_DIM, H_DIM, 0);
        gemm_bt<2, false><<<gg, 256, 0, stream>>>(Q_b, W2T, b2, cf_f32, nullptr, S_LEN, H_DIM, H_DIM, 0);
        float* of = (layer == 5) ? (float*)d_out : t_f32;
        add_layernorm<<<S_LEN, 256, 0, stream>>>(t_f32, cf_f32, of, t_b);
    }
}

// Round 7
// 630.286 us; speedup vs baseline: 1.5225x; 1.0043x over previous
//
#include <hip/hip_runtime.h>

#define S_LEN 2048
#define H_DIM 1024
#define NHEAD 8
#define D_HEAD 128
#define KSPLIT 4
#define KV_PER (S_LEN / KSPLIT)  // 512 kv positions per split

typedef __bf16 bf16x8 __attribute__((ext_vector_type(8)));
typedef float floatx4 __attribute__((ext_vector_type(4)));

__device__ __forceinline__ float b2f(unsigned short u) {
    union { unsigned int i; float f; } v;
    v.i = ((unsigned int)u) << 16;
    return v.f;
}
__device__ __forceinline__ unsigned short f2b(float f) {
    union { float f; unsigned int i; } v;
    v.f = f;
    return (unsigned short)((v.i + 0x7fffu + ((v.i >> 16) & 1u)) >> 16);
}

// async global->LDS DMA, 16 B per lane; lds dst = wave-uniform base + lane*16
__device__ __forceinline__ void dma16(void* lds, const void* g) {
    __builtin_amdgcn_global_load_lds(
        (const __attribute__((address_space(1))) void*)g,
        (__attribute__((address_space(3))) void*)lds, 16, 0, 0);
}

// ---------------- positional encoding + input add (fp32 in -> fp32 + bf16 out) ----------------
__global__ __launch_bounds__(256) void posenc_kernel(
    const float* __restrict__ in, float* __restrict__ xf,
    unsigned short* __restrict__ xb)
{
    int g = blockIdx.x * 256 + threadIdx.x;
    int s = g >> 10;
    int h = g & 1023;
    float dv = powf(10000.0f, -(float)h * (1.0f / 512.0f));
    float ang = (float)s * dv;
    float pe = (h & 1) ? cosf(ang) : sinf(ang);
    float x = in[g] + pe;
    xf[g] = x;
    xb[g] = f2b(x);
}

// ---------------- fp32 -> bf16 transpose (per head, [R,C] -> [C,R]) ----------------
__global__ __launch_bounds__(256) void transpose_f2b(
    const float* __restrict__ in, unsigned short* __restrict__ out, int R, int C)
{
    __shared__ unsigned short tile[32][33];
    const float* ih = in + (size_t)blockIdx.z * R * C;
    unsigned short* oh = out + (size_t)blockIdx.z * R * C;
    int r0 = blockIdx.y * 32, c0 = blockIdx.x * 32;
    int tx = threadIdx.x, ty = threadIdx.y;
    for (int i = ty; i < 32; i += 8)
        tile[i][tx] = f2b(ih[(size_t)(r0 + i) * C + c0 + tx]);
    __syncthreads();
    for (int i = ty; i < 32; i += 8)
        oh[(size_t)(c0 + i) * R + r0 + tx] = tile[tx][i];
}

// ---------------- GEMM: C[M,N] = A[M,K] @ Bt[N,K]^T + bias ----------------
// 64x64 tile, BK=64, global_load_lds staging into XOR-swizzled unpadded tiles,
// double-buffered LDS: DMA of slab k+1 overlaps MFMAs on slab k. 512 blocks.
// MODE 0: bf16 out [M,N]; MODE 1: bf16 out transposed [N, ldt]; MODE 2: f32 out [M,N]
template <int MODE, bool RELU>
__global__ __launch_bounds__(256, 4) void gemm_bt(
    const unsigned short* __restrict__ A, const unsigned short* __restrict__ Bt,
    const float* __restrict__ bias, float* __restrict__ Cf,
    unsigned short* __restrict__ Cb, int M, int N, int K, int ldt)
{
    __shared__ __align__(16) unsigned short sA[2][64 * 64];
    __shared__ __align__(16) unsigned short sB[2][64 * 64];
    const int tid = threadIdx.x;
    const int wave = tid >> 6, lane = tid & 63;
    const int quad = lane >> 4, l16 = lane & 15;
    const int i0 = blockIdx.y * 64, j0 = blockIdx.x * 64;
    const int wm = (wave >> 1) * 32, wn = (wave & 1) * 32;

    const int srow = lane >> 3;                       // 0..7 within wave group
    const int schunk = (lane & 7) ^ (srow & 7);       // global chunk to fetch (XOR swizzle)
    const unsigned short* Ap0 = A + (size_t)(i0 + wave * 8 + srow) * K + schunk * 8;
    const unsigned short* Ap1 = A + (size_t)(i0 + 32 + wave * 8 + srow) * K + schunk * 8;
    const unsigned short* Bp0 = Bt + (size_t)(j0 + wave * 8 + srow) * K + schunk * 8;
    const unsigned short* Bp1 = Bt + (size_t)(j0 + 32 + wave * 8 + srow) * K + schunk * 8;
    const int ld0 = (wave * 8) * 64, ld1 = (32 + wave * 8) * 64;

    floatx4 z4 = {0.f, 0.f, 0.f, 0.f};
    floatx4 acc[2][2];
#pragma unroll
    for (int i = 0; i < 2; i++)
#pragma unroll
        for (int j = 0; j < 2; j++) acc[i][j] = z4;

    dma16(sA[0] + ld0, Ap0);
    dma16(sA[0] + ld1, Ap1);
    dma16(sB[0] + ld0, Bp0);
    dma16(sB[0] + ld1, Bp1);
    __syncthreads();

    int buf = 0;
    for (int k0 = 0; k0 < K; k0 += 64) {
        if (k0 + 64 < K) {
            dma16(sA[buf ^ 1] + ld0, Ap0 + k0 + 64);
            dma16(sA[buf ^ 1] + ld1, Ap1 + k0 + 64);
            dma16(sB[buf ^ 1] + ld0, Bp0 + k0 + 64);
            dma16(sB[buf ^ 1] + ld1, Bp1 + k0 + 64);
        }
        const unsigned short* cA = sA[buf];
        const unsigned short* cB = sB[buf];
#pragma unroll
        for (int kh = 0; kh < 2; kh++) {
            bf16x8 af[2], bfr[2];
#pragma unroll
            for (int mi = 0; mi < 2; mi++) {
                int row = wm + mi * 16 + l16;
                int p = (kh * 4 + quad) ^ (l16 & 7);
                af[mi] = *(const bf16x8*)(cA + row * 64 + p * 8);
            }
#pragma unroll
            for (int ni = 0; ni < 2; ni++) {
                int row = wn + ni * 16 + l16;
                int p = (kh * 4 + quad) ^ (l16 & 7);
                bfr[ni] = *(const bf16x8*)(cB + row * 64 + p * 8);
            }
#pragma unroll
            for (int mi = 0; mi < 2; mi++)
#pragma unroll
                for (int ni = 0; ni < 2; ni++)
                    acc[mi][ni] = __builtin_amdgcn_mfma_f32_16x16x32_bf16(
                        af[mi], bfr[ni], acc[mi][ni], 0, 0, 0);
        }
        __syncthreads();
        buf ^= 1;
    }

#pragma unroll
    for (int mi = 0; mi < 2; mi++) {
#pragma unroll
        for (int ni = 0; ni < 2; ni++) {
            const int col = j0 + wn + ni * 16 + l16;
            const float bval = bias[col];
#pragma unroll
            for (int r = 0; r < 4; r++) {
                const int row_o = i0 + wm + mi * 16 + quad * 4 + r;  // C/D: row=quad*4+reg
                float v = acc[mi][ni][r] + bval;
                if (RELU) v = fmaxf(v, 0.0f);
                if (MODE == 0) Cb[(size_t)row_o * N + col] = f2b(v);
                else if (MODE == 1) Cb[(size_t)col * ldt + row_o] = f2b(v);
                else Cf[(size_t)row_o * N + col] = v;
            }
        }
    }
}

// ---------------- flash attention, q-tile=128, KV-split, no-max softmax, DMA staging ----
// block = (128 q rows, head, split); wave owns 32 q rows (2 m-halves of 16).
// Per 64-kv iter: 64 wave-MFMAs vs 36 b128 reads (bk/bv amortized over both m-halves),
// 2 barriers. sP is wave-private (padded stride 72) -> no P barrier.
// __launch_bounds__(256,2): 256-reg budget (need ~185; rounds 4/5 proved under-budgeting spills).
__global__ __launch_bounds__(256, 2) void flash_attn(
    const unsigned short* __restrict__ Qg, const unsigned short* __restrict__ Kg,
    const unsigned short* __restrict__ Vt, unsigned short* __restrict__ Op,
    float* __restrict__ Lp)
{
    __shared__ __align__(16) unsigned short sK[64 * 128];   // [t][d], chunk swz key row&15
    __shared__ __align__(16) unsigned short sV[128 * 64];   // [d][t], chunk swz key row&7
    __shared__ __align__(16) unsigned short sP[4 * 32 * 72];// per-wave P, padded stride

    const int tid = threadIdx.x;
    const int wave = tid >> 6, lane = tid & 63;
    const int quad = lane >> 4, l16 = lane & 15;
    const int head = blockIdx.y;
    const int q0 = blockIdx.x * 128;
    const int split = blockIdx.z;
    const int h0 = head * D_HEAD;

    // Q fragments direct from global (loop-invariant), 2 m-halves x 4 ks
    bf16x8 aq[2][4];
#pragma unroll
    for (int m = 0; m < 2; m++) {
        const int qrow = q0 + wave * 32 + m * 16 + l16;
#pragma unroll
        for (int ks = 0; ks < 4; ks++)
            aq[m][ks] = *(const bf16x8*)(Qg + (size_t)qrow * H_DIM + h0 + ks * 32 + quad * 8);
    }

    unsigned short* myP = sP + wave * (32 * 72);

    // K staging: 16 lanes/row, 4 rows/instr/wave; V: 8 lanes/row, 8 rows/instr/wave
    const int k_r = wave * 4 + (lane >> 4);
    const int k_c = (lane & 15) ^ (k_r & 15);
    const int v_r = wave * 8 + (lane >> 3);
    const int v_c = (lane & 7) ^ (v_r & 7);

    const unsigned short* Kbase = Kg + h0;
    const unsigned short* Vbase = Vt + (size_t)h0 * S_LEN;
    const int kt0 = split * KV_PER;

    floatx4 z4 = {0.f, 0.f, 0.f, 0.f};
    floatx4 o[2][8];
#pragma unroll
    for (int m = 0; m < 2; m++)
#pragma unroll
        for (int i = 0; i < 8; i++) o[m][i] = z4;
    float l_r[2][4] = {{0.f, 0.f, 0.f, 0.f}, {0.f, 0.f, 0.f, 0.f}};

    for (int it0 = 0; it0 < KV_PER; it0 += 64) {
        const int t0 = kt0 + it0;
        __syncthreads();  // (a) prior QK reads of sK + PV reads of sV done
#pragma unroll
        for (int it = 0; it < 4; it++) {
            dma16(sK + (wave * 4 + it * 16) * 128,
                  Kbase + (size_t)(t0 + k_r + it * 16) * H_DIM + k_c * 8);
            dma16(sV + (wave * 8 + it * 32) * 64,
                  Vbase + (size_t)(v_r + it * 32) * S_LEN + t0 + v_c * 8);
        }
        __syncthreads();  // (b) vmcnt drained -> tiles visible

        // scores S[32 q][64 t] = Q K^T; bk read once per (ni,ks), reused across m
        floatx4 sc[2][4];
#pragma unroll
        for (int m = 0; m < 2; m++)
#pragma unroll
            for (int ni = 0; ni < 4; ni++) sc[m][ni] = z4;
#pragma unroll
        for (int ni = 0; ni < 4; ni++) {
#pragma unroll
            for (int ks = 0; ks < 4; ks++) {
                int p = (ks * 4 + quad) ^ l16;
                bf16x8 bk = *(const bf16x8*)(sK + (ni * 16 + l16) * 128 + p * 8);
#pragma unroll
                for (int m = 0; m < 2; m++)
                    sc[m][ni] = __builtin_amdgcn_mfma_f32_16x16x32_bf16(
                        aq[m][ks], bk, sc[m][ni], 0, 0, 0);
            }
        }

        // exp without max subtraction (scores provably small); per-lane l partial
#pragma unroll
        for (int m = 0; m < 2; m++)
#pragma unroll
            for (int ni = 0; ni < 4; ni++)
#pragma unroll
                for (int r = 0; r < 4; r++) {
                    float p = __expf(sc[m][ni][r] * 0.03125f);  // 1/sqrt(H)=1/32
                    sc[m][ni][r] = p;
                    l_r[m][r] += p;
                }

        // P: C-layout -> wave-private padded LDS -> A-layout (no barrier needed)
#pragma unroll
        for (int m = 0; m < 2; m++)
#pragma unroll
            for (int ni = 0; ni < 4; ni++)
#pragma unroll
                for (int r = 0; r < 4; r++) {
                    int prow = m * 16 + quad * 4 + r;
                    myP[prow * 72 + ((ni * 16 + l16) ^ ((prow & 8) << 1))] = f2b(sc[m][ni][r]);
                }
        bf16x8 ap[2][2];
#pragma unroll
        for (int m = 0; m < 2; m++)
#pragma unroll
            for (int ks = 0; ks < 2; ks++)
                ap[m][ks] = *(const bf16x8*)(myP + (m * 16 + l16) * 72 +
                                             ((ks * 32 + quad * 8) ^ ((l16 & 8) << 1)));
        // PV: bv read once per (ni,ks), reused across m
#pragma unroll
        for (int ni = 0; ni < 8; ni++) {
#pragma unroll
            for (int ks = 0; ks < 2; ks++) {
                int p = (ks * 4 + quad) ^ (l16 & 7);
                bf16x8 bv = *(const bf16x8*)(sV + (ni * 16 + l16) * 64 + p * 8);
#pragma unroll
                for (int m = 0; m < 2; m++)
                    o[m][ni] = __builtin_amdgcn_mfma_f32_16x16x32_bf16(
                        ap[m][ks], bv, o[m][ni], 0, 0, 0);
            }
        }
    }

    // one-time l reduction across the 16-lane groups
#pragma unroll
    for (int m = 0; m < 2; m++)
#pragma unroll
        for (int r = 0; r < 4; r++)
#pragma unroll
            for (int off = 1; off < 16; off <<= 1)
                l_r[m][r] += __shfl_xor(l_r[m][r], off, 64);

#pragma unroll
    for (int m = 0; m < 2; m++)
#pragma unroll
        for (int r = 0; r < 4; r++) {
            float inv = 1.0f / l_r[m][r];
            int row = q0 + wave * 32 + m * 16 + quad * 4 + r;
#pragma unroll
            for (int ni = 0; ni < 8; ni++)
                Op[((size_t)split * S_LEN + row) * H_DIM + h0 + ni * 16 + l16] =
                    f2b(o[m][ni][r] * inv);
            if (l16 == 0)
                Lp[(split * NHEAD + head) * S_LEN + row] = l_r[m][r];
        }
}

// ---------------- merge KV-split partials + residual add + LayerNorm ----------------
__global__ __launch_bounds__(256) void merge_add_layernorm(
    const float* __restrict__ t, const unsigned short* __restrict__ Op,
    const float* __restrict__ Lp,
    float* __restrict__ of, unsigned short* __restrict__ ob)
{
    __shared__ float red[8];
    const int row = blockIdx.x, tid = threadIdx.x;
    const int head = tid >> 5;  // 32 threads per head (128 dims / 4)
    const size_t base = (size_t)row * H_DIM + tid * 4;

    float l_s[KSPLIT];
    ushort4 os[KSPLIT];
#pragma unroll
    for (int sp = 0; sp < KSPLIT; sp++) {
        os[sp] = *(const ushort4*)(Op + ((size_t)sp * S_LEN + row) * H_DIM + tid * 4);
        l_s[sp] = Lp[(sp * NHEAD + head) * S_LEN + row];
    }
    float W = 0.f, a0 = 0.f, a1 = 0.f, a2 = 0.f, a3 = 0.f;
#pragma unroll
    for (int sp = 0; sp < KSPLIT; sp++) {
        float w = l_s[sp];  // no-max softmax: weight is the raw partial sum
        W += w;
        a0 += w * b2f(os[sp].x);
        a1 += w * b2f(os[sp].y);
        a2 += w * b2f(os[sp].z);
        a3 += w * b2f(os[sp].w);
    }
    float inv = 1.0f / W;
    float4 x = *(const float4*)(t + base);
    float v0 = x.x + a0 * inv, v1 = x.y + a1 * inv;
    float v2 = x.z + a2 * inv, v3 = x.w + a3 * inv;

    float s = v0 + v1 + v2 + v3;
    float q = v0 * v0 + v1 * v1 + v2 * v2 + v3 * v3;
#pragma unroll
    for (int off = 32; off >= 1; off >>= 1) {
        s += __shfl_xor(s, off, 64);
        q += __shfl_xor(q, off, 64);
    }
    if ((tid & 63) == 0) { red[tid >> 6] = s; red[4 + (tid >> 6)] = q; }
    __syncthreads();
    s = red[0] + red[1] + red[2] + red[3];
    q = red[4] + red[5] + red[6] + red[7];
    const float mean = s * (1.0f / (float)H_DIM);
    const float var = q * (1.0f / (float)H_DIM) - mean * mean;
    const float rstd = rsqrtf(var + 1e-5f);
    float o0 = (v0 - mean) * rstd, o1 = (v1 - mean) * rstd;
    float o2 = (v2 - mean) * rstd, o3 = (v3 - mean) * rstd;
    *(float4*)(of + base) = make_float4(o0, o1, o2, o3);
    *(ushort4*)(ob + base) = make_ushort4(f2b(o0), f2b(o1), f2b(o2), f2b(o3));
}

// ---------------- fused residual add + LayerNorm (fp32 in -> fp32 + bf16 out) ----------------
__global__ __launch_bounds__(256) void add_layernorm(
    const float* __restrict__ a, const float* __restrict__ b,
    float* __restrict__ of, unsigned short* __restrict__ ob)
{
    __shared__ float red[8];
    const int row = blockIdx.x, tid = threadIdx.x;
    const size_t base = (size_t)row * H_DIM + tid * 4;
    float4 x = *(const float4*)(a + base);
    float4 y = *(const float4*)(b + base);
    float v0 = x.x + y.x, v1 = x.y + y.y, v2 = x.z + y.z, v3 = x.w + y.w;
    float s = v0 + v1 + v2 + v3;
    float q = v0 * v0 + v1 * v1 + v2 * v2 + v3 * v3;
#pragma unroll
    for (int off = 32; off >= 1; off >>= 1) {
        s += __shfl_xor(s, off, 64);
        q += __shfl_xor(q, off, 64);
    }
    if ((tid & 63) == 0) { red[tid >> 6] = s; red[4 + (tid >> 6)] = q; }
    __syncthreads();
    s = red[0] + red[1] + red[2] + red[3];
    q = red[4] + red[5] + red[6] + red[7];
    const float mean = s * (1.0f / (float)H_DIM);
    const float var = q * (1.0f / (float)H_DIM) - mean * mean;
    const float rstd = rsqrtf(var + 1e-5f);
    float o0 = (v0 - mean) * rstd, o1 = (v1 - mean) * rstd;
    float o2 = (v2 - mean) * rstd, o3 = (v3 - mean) * rstd;
    *(float4*)(of + base) = make_float4(o0, o1, o2, o3);
    *(ushort4*)(ob + base) = make_ushort4(f2b(o0), f2b(o1), f2b(o2), f2b(o3));
}

extern "C" void kernel_launch(void* const* d_in, const int* in_sizes, int n_in,
                              void* d_out, int out_size, void* d_ws, size_t ws_size,
                              hipStream_t stream)
{
    (void)in_sizes; (void)n_in; (void)out_size; (void)ws_size;
    const float* in = (const float*)d_in[0];
    const float* Wq = (const float*)d_in[1];
    const float* bq = (const float*)d_in[2];
    const float* Wk = (const float*)d_in[3];
    const float* bk = (const float*)d_in[4];
    const float* Wv = (const float*)d_in[5];
    const float* bv = (const float*)d_in[6];
    const float* W1 = (const float*)d_in[7];
    const float* b1 = (const float*)d_in[8];
    const float* W2 = (const float*)d_in[9];
    const float* b2 = (const float*)d_in[10];

    char* ws = (char*)d_ws;
    const size_t MB = 1024 * 1024;
    float* t_f32 = (float*)(ws + 0 * MB);                    // 8 MB
    float* cf_f32 = (float*)(ws + 8 * MB);                   // 8 MB (ff2)
    unsigned short* t_b = (unsigned short*)(ws + 16 * MB);   // 4 MB
    unsigned short* K_b = (unsigned short*)(ws + 20 * MB);   // 4 MB
    unsigned short* Vt_b = (unsigned short*)(ws + 24 * MB);  // 4 MB, [NH,D,S]
    unsigned short* Q_b = (unsigned short*)(ws + 28 * MB);   // 4 MB (also ff1)
    unsigned short* WqT = (unsigned short*)(ws + 32 * MB);   // 2 MB each, [N,K]
    unsigned short* WkT = (unsigned short*)(ws + 34 * MB);
    unsigned short* WvT = (unsigned short*)(ws + 36 * MB);
    unsigned short* W1T = (unsigned short*)(ws + 38 * MB);
    unsigned short* W2T = (unsigned short*)(ws + 40 * MB);
    unsigned short* Op = (unsigned short*)(ws + 42 * MB);    // 16 MB [split][S][H] bf16
    float* Lp = (float*)(ws + 58 * MB);                      // 256 KB [split][NH][S]

    dim3 tb(32, 8);
    transpose_f2b<<<dim3(4, 32, 8), tb, 0, stream>>>(Wq, WqT, H_DIM, D_HEAD);
    transpose_f2b<<<dim3(4, 32, 8), tb, 0, stream>>>(Wk, WkT, H_DIM, D_HEAD);
    transpose_f2b<<<dim3(4, 32, 8), tb, 0, stream>>>(Wv, WvT, H_DIM, D_HEAD);
    transpose_f2b<<<dim3(32, 32, 1), tb, 0, stream>>>(W1, W1T, H_DIM, H_DIM);
    transpose_f2b<<<dim3(32, 32, 1), tb, 0, stream>>>(W2, W2T, H_DIM, H_DIM);

    posenc_kernel<<<(S_LEN * H_DIM) / 256, 256, 0, stream>>>(in, t_f32, t_b);

    dim3 gg(H_DIM / 64, S_LEN / 64);  // 16 x 32 = 512 blocks
    gemm_bt<0, false><<<gg, 256, 0, stream>>>(t_b, WkT, bk, nullptr, K_b, S_LEN, H_DIM, H_DIM, 0);
    gemm_bt<1, false><<<gg, 256, 0, stream>>>(t_b, WvT, bv, nullptr, Vt_b, S_LEN, H_DIM, H_DIM, S_LEN);

    for (int layer = 0; layer < 6; layer++) {
        gemm_bt<0, false><<<gg, 256, 0, stream>>>(t_b, WqT, bq, nullptr, Q_b, S_LEN, H_DIM, H_DIM, 0);
        flash_attn<<<dim3(S_LEN / 128, NHEAD, KSPLIT), 256, 0, stream>>>(Q_b, K_b, Vt_b, Op, Lp);
        merge_add_layernorm<<<S_LEN, 256, 0, stream>>>(t_f32, Op, Lp, t_f32, t_b);
        gemm_bt<0, true><<<gg, 256, 0, stream>>>(t_b, W1T, b1, nullptr, Q_b, S_LEN, H_DIM, H_DIM, 0);
        gemm_bt<2, false><<<gg, 256, 0, stream>>>(Q_b, W2T, b2, cf_f32, nullptr, S_LEN, H_DIM, H_DIM, 0);
        float* of = (layer == 5) ? (float*)d_out : t_f32;
        add_layernorm<<<S_LEN, 256, 0, stream>>>(t_f32, cf_f32, of, t_b);
    }
}